// Round 16
// baseline (106.368 us; speedup 1.0000x reference)
//
#include <hip/hip_runtime.h>
#include <hip/hip_bf16.h>
#include <stdint.h>

#define SS 4096
#define DD 256
#define HH 4
#define KK 64
#define ALPHA 0.18033688011112042f  // 0.125 * log2(e)

typedef float f32x4 __attribute__((ext_vector_type(4)));
typedef short s16x8 __attribute__((ext_vector_type(8)));
typedef unsigned int u32;

__device__ __forceinline__ unsigned short f2bf(float x) {
  union { float f; unsigned u; } v; v.f = x;
  unsigned r = v.u + 0x7fffu + ((v.u >> 16) & 1u);
  return (unsigned short)(r >> 16);
}

__device__ __forceinline__ u32 cvtpk(float lo, float hi) {
  u32 r;
  asm("v_cvt_pk_bf16_f32 %0, %1, %2" : "=v"(r) : "v"(lo), "v"(hi));
  return r;
}

// hardware 2^x via compiler intrinsic (hazard-safe, single v_exp_f32)
#define fexp2(x) __builtin_amdgcn_exp2f(x)

__device__ __forceinline__ void gl_lds16(const unsigned short* g, unsigned short* l) {
  __builtin_amdgcn_global_load_lds(
      (const __attribute__((address_space(1))) u32*)g,
      (__attribute__((address_space(3))) u32*)l, 16, 0, 0);
}

// ---------------- Kernel 0: weight prep (tiled LDS transpose, coalesced) ----------------
// 64 blocks = mat(4: Wq,Wk,Wv,Wo) x ti(4) x tj(4), 64x64 tiles.
// dst[i][j] = sc * src[j][i]; loads coalesced f32x4, stores coalesced 16B.
__global__ void wprep(const float* __restrict__ Wq, const float* __restrict__ Wk,
                      const float* __restrict__ Wv, const float* __restrict__ Wo,
                      unsigned short* __restrict__ Wt, unsigned short* __restrict__ Wot)
{
  __shared__ unsigned short L[64][72];
  const int blk = blockIdx.x;
  const int mat = blk >> 4;
  const int ti = (blk >> 2) & 3;
  const int tj = blk & 3;
  const int t = threadIdx.x;
  const float sc = (mat == 0) ? ALPHA : 1.0f;
  const float* src = (mat == 0) ? Wq : (mat == 1) ? Wk : (mat == 2) ? Wv : Wo;
  unsigned short* dst = (mat < 3) ? (Wt + (size_t)mat * 256 * 256) : Wot;
  const int i0 = ti * 64, j0 = tj * 64;

  {
    const int jj = t >> 4;            // 0..15, 4 passes
    const int ii = (t & 15) * 4;
    #pragma unroll
    for (int p = 0; p < 4; ++p) {
      f32x4 v = *(const f32x4*)&src[(size_t)(j0 + jj + p * 16) * 256 + i0 + ii];
      uint2 pk; pk.x = cvtpk(sc * v[0], sc * v[1]); pk.y = cvtpk(sc * v[2], sc * v[3]);
      *(uint2*)&L[jj + p * 16][ii] = pk;
    }
  }
  __syncthreads();

  const int i = i0 + (t >> 2);
  const int jb = (t & 3) * 16;
  union { unsigned short u[16]; s16x8 v[2]; } pk;
  #pragma unroll
  for (int s = 0; s < 16; ++s) pk.u[s] = L[jb + s][t >> 2];
  *(s16x8*)&dst[(size_t)i * 256 + j0 + jb] = pk.v[0];
  *(s16x8*)&dst[(size_t)i * 256 + j0 + jb + 8] = pk.v[1];
}

// ---------------- Kernel 1: QKV projection (r13 version: per-matrix blocks) ----------------
__global__ __launch_bounds__(256, 3) void qkv_mfma(
    const float* __restrict__ query, const float* __restrict__ value,
    const unsigned short* __restrict__ Wt,
    const float* __restrict__ bq, const float* __restrict__ bk,
    const float* __restrict__ bv,
    unsigned short* __restrict__ qb, unsigned short* __restrict__ kbs,
    unsigned short* __restrict__ vts)
{
  __shared__ __align__(16) unsigned short Xs[64 * 256];   // 32 KB, swizzled

  const int t = threadIdx.x;
  const int w = t >> 6, l = t & 63, lr = l & 15, grp = l >> 4;
  const int mat = (int)(blockIdx.x % 3u);
  const int rb  = (int)(blockIdx.x / 3u);
  const long r0 = (long)rb * 64;

  const float* X = (mat == 0) ? query : value;

  {
    const int row = t >> 2;
    const int c0s = (t & 3) * 64;
    const float* xp = X + (r0 + row) * 256 + c0s;
    const int sw = (row & 7) << 3;
    #pragma unroll
    for (int g = 0; g < 8; ++g) {
      f32x4 x0 = *(const f32x4*)(xp + g * 8);
      f32x4 x1 = *(const f32x4*)(xp + g * 8 + 4);
      union { u32 wd[4]; s16x8 v; } bb;
      bb.wd[0] = cvtpk(x0[0], x0[1]);
      bb.wd[1] = cvtpk(x0[2], x0[3]);
      bb.wd[2] = cvtpk(x1[0], x1[1]);
      bb.wd[3] = cvtpk(x1[2], x1[3]);
      *(s16x8*)&Xs[(row * 256 + c0s + g * 8) ^ sw] = bb.v;
    }
  }
  __syncthreads();

  const int n0 = w * 64;                 // head w
  const int swr = (lr & 7) << 3;

  f32x4 acc[4][4] = {};

  #pragma unroll 2
  for (int k0 = 0; k0 < 256; k0 += 32) {
    s16x8 xf[4];
    #pragma unroll
    for (int mt = 0; mt < 4; ++mt)
      xf[mt] = *(const s16x8*)&Xs[((mt * 16 + lr) * 256 + k0 + grp * 8) ^ swr];
    #pragma unroll
    for (int nt = 0; nt < 4; ++nt) {
      s16x8 af = *(const s16x8*)(Wt + (size_t)(mat * 256 + n0 + nt * 16 + lr) * 256 + k0 + grp * 8);
      if (mat == 2) {
        #pragma unroll
        for (int mt = 0; mt < 4; ++mt)
          acc[mt][nt] = __builtin_amdgcn_mfma_f32_16x16x32_bf16(xf[mt], af, acc[mt][nt], 0, 0, 0);
      } else {
        #pragma unroll
        for (int mt = 0; mt < 4; ++mt)
          acc[mt][nt] = __builtin_amdgcn_mfma_f32_16x16x32_bf16(af, xf[mt], acc[mt][nt], 0, 0, 0);
      }
    }
  }

  const int b  = (int)(r0 >> 12);
  const int s0 = (int)(r0 & 4095);
  const int kt = s0 >> 6;
  const size_t base = (size_t)(b * 4 + w) * (SS * KK) + (size_t)kt * 4096;

  if (mat == 0) {
    #pragma unroll
    for (int nt = 0; nt < 4; ++nt) {
      const int nk = nt * 16 + grp * 4;
      f32x4 bias = *(const f32x4*)&bq[n0 + nk] * ALPHA;
      #pragma unroll
      for (int mt = 0; mt < 4; ++mt) {
        const int s = s0 + mt * 16 + lr;
        f32x4 o = acc[mt][nt] + bias;
        uint2 pk2; pk2.x = cvtpk(o[0], o[1]); pk2.y = cvtpk(o[2], o[3]);
        *(uint2*)&qb[((size_t)(b * 4 + w) * SS + s) * KK + nk] = pk2;
      }
    }
  } else if (mat == 1) {
    #pragma unroll
    for (int nt = 0; nt < 4; ++nt) {
      const int d0 = nt * 16 + grp * 4;
      const int cc = d0 >> 5, grpk = (d0 >> 3) & 3, jlo = d0 & 7;
      f32x4 bias = *(const f32x4*)&bk[n0 + d0];
      #pragma unroll
      for (int mt = 0; mt < 4; ++mt) {
        const int chunk = ((mt * 2 + cc) * 4 + grpk) * 16 + lr;
        f32x4 o = acc[mt][nt] + bias;
        uint2 pk2; pk2.x = cvtpk(o[0], o[1]); pk2.y = cvtpk(o[2], o[3]);
        *(uint2*)&kbs[base + chunk * 8 + jlo] = pk2;
      }
    }
  } else {
    #pragma unroll
    for (int nt = 0; nt < 4; ++nt) {
      const float bvn = bv[n0 + nt * 16 + lr];
      #pragma unroll
      for (int mt = 0; mt < 4; ++mt) {
        const int cb = (nt * 2 + (mt >> 1)) * 64 + grp * 16 + lr;
        f32x4 o = acc[mt][nt] + bvn;
        uint2 pk2; pk2.x = cvtpk(o[0], o[1]); pk2.y = cvtpk(o[2], o[3]);
        *(uint2*)&vts[base + (size_t)cb * 8 + (mt & 1) * 4] = pk2;
      }
    }
  }
}

// ---------------- Kernel 2: causal flash attention (unchanged from r13) ----------------
__global__ __launch_bounds__(256, 4) void attn(
    const unsigned short* __restrict__ qb,
    const unsigned short* __restrict__ kbs,
    const unsigned short* __restrict__ vts,
    unsigned short* __restrict__ ns0, unsigned short* __restrict__ ns2,
    float* __restrict__ lb0, float* __restrict__ lb2)
{
  __shared__ __align__(16) unsigned short Kl[2][4096];
  __shared__ __align__(16) unsigned short Vl[2][4096];
  __shared__ float lred[2][2][16];

  const int t = threadIdx.x;
  const int w = t >> 6, l = t & 63, lr = l & 15, grp = l >> 4;
  const int qg = w >> 1, kh = w & 1;

  const int i    = blockIdx.x;
  const int bh   = i & 15;
  const int pr   = (i >> 4) & 31;
  const int role = (i >> 9) & 1;
  const int b = bh >> 2, h = bh & 3;

  const unsigned short* kbase = kbs + (size_t)bh * (SS * KK);
  const unsigned short* vbase = vts + (size_t)bh * (SS * KK);
  const unsigned short* qpb   = qb  + (size_t)bh * (SS * KK);

  int sup = (role == 0) ? pr : (63 - pr);
  const int nsteps = 33 - role;

  s16x8 qf[2][2];
  #pragma unroll
  for (int q2 = 0; q2 < 2; ++q2) {
    const unsigned short* qp = qpb + (size_t)(sup * 64 + qg * 32 + q2 * 16 + lr) * KK;
    qf[q2][0] = *(const s16x8*)(qp + grp * 8);
    qf[q2][1] = *(const s16x8*)(qp + 32 + grp * 8);
  }

  s16x8 ones;
  #pragma unroll
  for (int e = 0; e < 8; ++e) ones[e] = (short)0x3F80;   // bf16 1.0
  const f32x4 minit = {-16.f, -16.f, -16.f, -16.f};

  f32x4 cacc[2][4] = {};
  f32x4 lacc[2] = {};

  const int off0 = (w * 64 + l) * 8;
  const int off1 = ((4 + w) * 64 + l) * 8;

  auto ktfor = [&](int s) {
    return (role == 0) ? ((s <= pr) ? s : (s - (pr + 1))) : (32 - pr + s);
  };
  auto stage = [&](int kt, int bi) {
    const unsigned short* ks = kbase + (size_t)kt * 4096;
    const unsigned short* vs = vbase + (size_t)kt * 4096;
    gl_lds16(ks + off0, &Kl[bi][w * 512]);
    gl_lds16(ks + off1, &Kl[bi][(4 + w) * 512]);
    gl_lds16(vs + off0, &Vl[bi][w * 512]);
    gl_lds16(vs + off1, &Vl[bi][(4 + w) * 512]);
  };

  auto merge_kh = [&](int cur) {
    float* mb0 = (float*)&Kl[cur][0];   // q2 = 0
    float* mb1 = (float*)&Vl[cur][0];   // q2 = 1
    if (kh == 1) {
      #pragma unroll
      for (int m2 = 0; m2 < 4; ++m2)
        #pragma unroll
        for (int e = 0; e < 4; ++e) {
          mb0[(m2 * 4 + e) * 128 + qg * 64 + l] = cacc[0][m2][e];
          mb1[(m2 * 4 + e) * 128 + qg * 64 + l] = cacc[1][m2][e];
        }
      if (grp == 0) { lred[qg][0][lr] = lacc[0][0]; lred[qg][1][lr] = lacc[1][0]; }
    }
    __syncthreads();
    if (kh == 0) {
      #pragma unroll
      for (int m2 = 0; m2 < 4; ++m2)
        #pragma unroll
        for (int e = 0; e < 4; ++e) {
          cacc[0][m2][e] += mb0[(m2 * 4 + e) * 128 + qg * 64 + l];
          cacc[1][m2][e] += mb1[(m2 * 4 + e) * 128 + qg * 64 + l];
        }
    }
  };

  stage(ktfor(0), 0);
  __syncthreads();

  for (int ss = 0; ss < nsteps; ++ss) {
    const int cur = ss & 1;
    if (ss + 1 < nsteps) stage(ktfor(ss + 1), cur ^ 1);

    const int kt = ktfor(ss);
    const unsigned short* Kb = &Kl[cur][0];
    const unsigned short* Vb = &Vl[cur][0];

    s16x8 kf[4];
    #pragma unroll
    for (int j = 0; j < 4; ++j)
      kf[j] = *(const s16x8*)&Kb[(((kh * 4 + j) * 4 + grp) * 16 + lr) * 8];

    __builtin_amdgcn_s_setprio(1);
    f32x4 sc[2][2];
    #pragma unroll
    for (int q2 = 0; q2 < 2; ++q2) {
      #pragma unroll
      for (int tt = 0; tt < 2; ++tt) {
        f32x4 a = __builtin_amdgcn_mfma_f32_16x16x32_bf16(kf[tt * 2 + 0], qf[q2][0], minit, 0, 0, 0);
        a = __builtin_amdgcn_mfma_f32_16x16x32_bf16(kf[tt * 2 + 1], qf[q2][1], a, 0, 0, 0);
        sc[q2][tt] = a;
      }
    }
    __builtin_amdgcn_s_setprio(0);

    if (kt == sup) {
      #pragma unroll
      for (int q2 = 0; q2 < 2; ++q2) {
        const int qloc = qg * 32 + q2 * 16 + lr;
        #pragma unroll
        for (int tt = 0; tt < 2; ++tt)
          #pragma unroll
          for (int e = 0; e < 4; ++e)
            if (((kh * 2 + tt) * 16 + grp * 4 + e) > qloc) sc[q2][tt][e] += -1.0e9f;
      }
    }

    #pragma unroll
    for (int q2 = 0; q2 < 2; ++q2)
      #pragma unroll
      for (int tt = 0; tt < 2; ++tt)
        #pragma unroll
        for (int e = 0; e < 4; ++e)
          sc[q2][tt][e] = fexp2(sc[q2][tt][e]);

    s16x8 pf[2];
    #pragma unroll
    for (int q2 = 0; q2 < 2; ++q2) {
      union { u32 wd[4]; s16x8 v; } pu;
      pu.wd[0] = cvtpk(sc[q2][0][0], sc[q2][0][1]);
      pu.wd[1] = cvtpk(sc[q2][0][2], sc[q2][0][3]);
      pu.wd[2] = cvtpk(sc[q2][1][0], sc[q2][1][1]);
      pu.wd[3] = cvtpk(sc[q2][1][2], sc[q2][1][3]);
      pf[q2] = pu.v;
    }

    __builtin_amdgcn_s_setprio(1);
    #pragma unroll
    for (int m2 = 0; m2 < 4; ++m2) {
      s16x8 vfr = *(const s16x8*)&Vb[((m2 * 2 + kh) * 64 + l) * 8];
      cacc[0][m2] = __builtin_amdgcn_mfma_f32_16x16x32_bf16(vfr, pf[0], cacc[0][m2], 0, 0, 0);
      cacc[1][m2] = __builtin_amdgcn_mfma_f32_16x16x32_bf16(vfr, pf[1], cacc[1][m2], 0, 0, 0);
    }
    lacc[0] = __builtin_amdgcn_mfma_f32_16x16x32_bf16(ones, pf[0], lacc[0], 0, 0, 0);
    lacc[1] = __builtin_amdgcn_mfma_f32_16x16x32_bf16(ones, pf[1], lacc[1], 0, 0, 0);
    __builtin_amdgcn_s_setprio(0);

    if (role == 0 && ss == pr) {
      __syncthreads();
      merge_kh(cur);
      if (kh == 0) {
        #pragma unroll
        for (int q2 = 0; q2 < 2; ++q2) {
          const int rowg = sup * 64 + qg * 32 + q2 * 16 + lr;
          unsigned short* np_ = ns0 + ((size_t)((b << 12) + rowg)) * 256 + h * 64;
          #pragma unroll
          for (int m2 = 0; m2 < 4; ++m2) {
            uint2 pk2; pk2.x = cvtpk(cacc[q2][m2][0], cacc[q2][m2][1]);
            pk2.y = cvtpk(cacc[q2][m2][2], cacc[q2][m2][3]);
            *(uint2*)&np_[m2 * 16 + grp * 4] = pk2;
          }
          if (grp == 0) lb0[(bh << 12) + rowg] = lacc[q2][0] + lred[qg][q2][lr];
        }
      }
      #pragma unroll
      for (int q2 = 0; q2 < 2; ++q2) {
        cacc[q2][0] = cacc[q2][1] = cacc[q2][2] = cacc[q2][3] = (f32x4){0.f, 0.f, 0.f, 0.f};
        lacc[q2] = (f32x4){0.f, 0.f, 0.f, 0.f};
      }
      sup = 63 - pr;
      #pragma unroll
      for (int q2 = 0; q2 < 2; ++q2) {
        const unsigned short* qp = qpb + (size_t)(sup * 64 + qg * 32 + q2 * 16 + lr) * KK;
        qf[q2][0] = *(const s16x8*)(qp + grp * 8);
        qf[q2][1] = *(const s16x8*)(qp + 32 + grp * 8);
      }
    }
    __syncthreads();
  }

  merge_kh((nsteps - 1) & 1);
  if (kh == 0) {
    if (role == 0) {
      #pragma unroll
      for (int q2 = 0; q2 < 2; ++q2) {
        const int rowg = sup * 64 + qg * 32 + q2 * 16 + lr;
        unsigned short* np_ = ns0 + ((size_t)((b << 12) + rowg)) * 256 + h * 64;
        #pragma unroll
        for (int m2 = 0; m2 < 4; ++m2) {
          uint2 pk2; pk2.x = cvtpk(cacc[q2][m2][0], cacc[q2][m2][1]);
          pk2.y = cvtpk(cacc[q2][m2][2], cacc[q2][m2][3]);
          *(uint2*)&np_[m2 * 16 + grp * 4] = pk2;
        }
        if (grp == 0) lb0[(bh << 12) + rowg] = lacc[q2][0] + lred[qg][q2][lr];
      }
    } else {
      #pragma unroll
      for (int q2 = 0; q2 < 2; ++q2) {
        const int rowg = sup * 64 + qg * 32 + q2 * 16 + lr;   // >= 2048
        unsigned short* np_ = ns2 + ((size_t)((b << 11) + (rowg - 2048))) * 256 + h * 64;
        #pragma unroll
        for (int m2 = 0; m2 < 4; ++m2) {
          uint2 pk2; pk2.x = cvtpk(cacc[q2][m2][0], cacc[q2][m2][1]);
          pk2.y = cvtpk(cacc[q2][m2][2], cacc[q2][m2][3]);
          *(uint2*)&np_[m2 * 16 + grp * 4] = pk2;
        }
        if (grp == 0) lb2[(bh << 11) + (rowg - 2048)] = lacc[q2][0] + lred[qg][q2][lr];
      }
    }
  }
}

// ---------------- Kernel 3: output projection + residual + LayerNorm (dual-MFMA merge) ----------------
// ns0-frag and ns2-frag feed the SAME accumulator as raw bf16 B-operands (sum
// distributes over MFMA); per-(row, h-block) 1/l scale applied on per-h-group
// accumulators (invl is a row scalar; D row = n via grp*4+e, col = row via lr).
__global__ __launch_bounds__(256, 4) void oproj_ln(
    const unsigned short* __restrict__ ns0, const unsigned short* __restrict__ ns2,
    const float* __restrict__ lb0, const float* __restrict__ lb2,
    const unsigned short* __restrict__ Wot,
    const float* __restrict__ bo, const float* __restrict__ query,
    const float* __restrict__ gamma, const float* __restrict__ beta,
    float* __restrict__ out)
{
  __shared__ __align__(16) float redS[32][4];
  __shared__ __align__(16) float redQ[32][4];

  const int t = threadIdx.x;
  const int w = t >> 6, l = t & 63, lr = l & 15, grp = l >> 4;
  const long r0 = (long)blockIdx.x * 32;
  const int n0c = w * 64;
  const int b = (int)(r0 >> 12);
  const bool heavy = ((r0 >> 11) & 1) != 0;

  float invl[2][4];
  #pragma unroll
  for (int mt = 0; mt < 2; ++mt) {
    const int grow = (int)r0 + mt * 16 + lr;
    #pragma unroll
    for (int h = 0; h < 4; ++h) {
      float lv = lb0[((b * 4 + h) << 12) + (grow & 4095)];
      if (heavy) lv += lb2[((b * 4 + h) << 11) + (grow & 2047)];
      invl[mt][h] = 1.0f / lv;
    }
  }

  f32x4 acc[2][4] = {};

  #pragma unroll
  for (int hh = 0; hh < 4; ++hh) {
    f32x4 acch[2][4] = {};
    #pragma unroll
    for (int kq = 0; kq < 2; ++kq) {
      const int c = hh * 64 + kq * 32 + grp * 8;
      s16x8 b0[2], b2[2];
      #pragma unroll
      for (int mt = 0; mt < 2; ++mt) {
        const int grow = (int)r0 + mt * 16 + lr;
        b0[mt] = *(const s16x8*)(ns0 + (size_t)grow * 256 + c);
        if (heavy)
          b2[mt] = *(const s16x8*)(ns2 + ((size_t)((b << 11) + (grow & 2047))) * 256 + c);
      }
      #pragma unroll
      for (int nt = 0; nt < 4; ++nt) {
        s16x8 af = *(const s16x8*)(Wot + (size_t)(n0c + nt * 16 + lr) * 256 + c);
        acch[0][nt] = __builtin_amdgcn_mfma_f32_16x16x32_bf16(af, b0[0], acch[0][nt], 0, 0, 0);
        acch[1][nt] = __builtin_amdgcn_mfma_f32_16x16x32_bf16(af, b0[1], acch[1][nt], 0, 0, 0);
        if (heavy) {
          acch[0][nt] = __builtin_amdgcn_mfma_f32_16x16x32_bf16(af, b2[0], acch[0][nt], 0, 0, 0);
          acch[1][nt] = __builtin_amdgcn_mfma_f32_16x16x32_bf16(af, b2[1], acch[1][nt], 0, 0, 0);
        }
      }
    }
    #pragma unroll
    for (int mt = 0; mt < 2; ++mt)
      #pragma unroll
      for (int nt = 0; nt < 4; ++nt)
        acc[mt][nt] += acch[mt][nt] * invl[mt][hh];
  }

  float sm[2] = {0.f, 0.f}, sq[2] = {0.f, 0.f};
  #pragma unroll
  for (int mt = 0; mt < 2; ++mt) {
    const long s = r0 + mt * 16 + lr;
    #pragma unroll
    for (int nt = 0; nt < 4; ++nt) {
      const int n = n0c + nt * 16 + grp * 4;
      f32x4 v = acc[mt][nt] + *(const f32x4*)&bo[n] + *(const f32x4*)&query[s * 256 + n];
      acc[mt][nt] = v;
      sm[mt] += v[0] + v[1] + v[2] + v[3];
      sq[mt] += v[0]*v[0] + v[1]*v[1] + v[2]*v[2] + v[3]*v[3];
    }
    sm[mt] += __shfl_xor(sm[mt], 16); sm[mt] += __shfl_xor(sm[mt], 32);
    sq[mt] += __shfl_xor(sq[mt], 16); sq[mt] += __shfl_xor(sq[mt], 32);
  }
  if (grp == 0) {
    redS[0 * 16 + lr][w] = sm[0]; redQ[0 * 16 + lr][w] = sq[0];
    redS[1 * 16 + lr][w] = sm[1]; redQ[1 * 16 + lr][w] = sq[1];
  }
  __syncthreads();

  #pragma unroll
  for (int mt = 0; mt < 2; ++mt) {
    f32x4 s4 = *(const f32x4*)&redS[mt * 16 + lr][0];
    f32x4 q4 = *(const f32x4*)&redQ[mt * 16 + lr][0];
    const float tot = s4[0] + s4[1] + s4[2] + s4[3];
    const float tq  = q4[0] + q4[1] + q4[2] + q4[3];
    const float mu  = tot * 0.00390625f;
    const float var = tq * 0.00390625f - mu * mu;
    const float rs  = rsqrtf(var + 1.0e-3f);
    const long s = r0 + mt * 16 + lr;
    #pragma unroll
    for (int nt = 0; nt < 4; ++nt) {
      const int n = n0c + nt * 16 + grp * 4;
      f32x4 g = *(const f32x4*)&gamma[n];
      f32x4 bt = *(const f32x4*)&beta[n];
      f32x4 o = (acc[mt][nt] - mu) * rs * g + bt;
      *(f32x4*)&out[s * 256 + n] = o;
    }
  }
}

extern "C" void kernel_launch(void* const* d_in, const int* in_sizes, int n_in,
                              void* d_out, int out_size, void* d_ws, size_t ws_size,
                              hipStream_t stream) {
  const float* query = (const float*)d_in[0];
  const float* value = (const float*)d_in[1];
  const float* Wq    = (const float*)d_in[2];
  const float* bq    = (const float*)d_in[3];
  const float* Wk    = (const float*)d_in[4];
  const float* bk    = (const float*)d_in[5];
  const float* Wv    = (const float*)d_in[6];
  const float* bv    = (const float*)d_in[7];
  const float* Wo    = (const float*)d_in[8];
  const float* bo    = (const float*)d_in[9];
  const float* gamma = (const float*)d_in[10];
  const float* beta  = (const float*)d_in[11];
  float* out = (float*)d_out;

  char* ws = (char*)d_ws;
  unsigned short* qb  = (unsigned short*)ws;                          //  8 MiB bf16 [bh][s][dk]
  unsigned short* kbs = (unsigned short*)(ws + ((size_t)8  << 20));   //  8 MiB bf16 chunked K
  unsigned short* vts = (unsigned short*)(ws + ((size_t)16 << 20));   //  8 MiB bf16 chunked V^T
  unsigned short* ns0 = (unsigned short*)(ws + ((size_t)24 << 20));   //  8 MiB bf16 [b*4096][256]
  unsigned short* ns2 = (unsigned short*)(ws + ((size_t)32 << 20));   //  4 MiB bf16 [b*2048][256]
  float* lb0 = (float*)(ws + ((size_t)36 << 20));                     // 256 KiB f32 [16][4096]
  float* lb2 = (float*)(ws + ((size_t)36 << 20) + ((size_t)256 << 10)); // 128 KiB f32 [16][2048]
  unsigned short* Wt  = (unsigned short*)(ws + ((size_t)36 << 20) + ((size_t)512 << 10)); // 384 KiB
  unsigned short* Wot = Wt + (size_t)768 * 256;                       // 128 KiB

  wprep<<<64, 256, 0, stream>>>(Wq, Wk, Wv, Wo, Wt, Wot);
  qkv_mfma<<<768, 256, 0, stream>>>(query, value, Wt, bq, bk, bv, qb, kbs, vts);
  attn<<<1024, 256, 0, stream>>>(qb, kbs, vts, ns0, ns2, lb0, lb2);
  oproj_ln<<<512, 256, 0, stream>>>(ns0, ns2, lb0, lb2, Wot, bo, query, gamma, beta, out);
}

// Round 17
// 101.102 us; speedup vs baseline: 1.0521x; 1.0521x over previous
//
#include <hip/hip_runtime.h>
#include <hip/hip_bf16.h>
#include <stdint.h>

#define SS 4096
#define DD 256
#define HH 4
#define KK 64
#define ALPHA 0.18033688011112042f  // 0.125 * log2(e)

typedef float f32x4 __attribute__((ext_vector_type(4)));
typedef short s16x8 __attribute__((ext_vector_type(8)));
typedef unsigned int u32;

__device__ __forceinline__ unsigned short f2bf(float x) {
  union { float f; unsigned u; } v; v.f = x;
  unsigned r = v.u + 0x7fffu + ((v.u >> 16) & 1u);
  return (unsigned short)(r >> 16);
}

__device__ __forceinline__ u32 cvtpk(float lo, float hi) {
  u32 r;
  asm("v_cvt_pk_bf16_f32 %0, %1, %2" : "=v"(r) : "v"(lo), "v"(hi));
  return r;
}

// hardware 2^x via compiler intrinsic (hazard-safe, single v_exp_f32)
#define fexp2(x) __builtin_amdgcn_exp2f(x)

__device__ __forceinline__ void gl_lds16(const unsigned short* g, unsigned short* l) {
  __builtin_amdgcn_global_load_lds(
      (const __attribute__((address_space(1))) u32*)g,
      (__attribute__((address_space(3))) u32*)l, 16, 0, 0);
}

// accumulate 8 bf16 (as shorts) into two f32x4
__device__ __forceinline__ void acc8(const unsigned short* p, f32x4& a0, f32x4& a1) {
  s16x8 v = *(const s16x8*)p;
  union { u32 u; float f; } c;
  #pragma unroll
  for (int j = 0; j < 4; ++j) { c.u = ((u32)(unsigned short)v[j]) << 16; a0[j] += c.f; }
  #pragma unroll
  for (int j = 0; j < 4; ++j) { c.u = ((u32)(unsigned short)v[4 + j]) << 16; a1[j] += c.f; }
}

// ---------------- Kernel 0: weight prep (256 blocks) ----------------
__global__ void wprep(const float* __restrict__ Wq, const float* __restrict__ Wk,
                      const float* __restrict__ Wv, const float* __restrict__ Wo,
                      unsigned short* __restrict__ Wt, unsigned short* __restrict__ Wot)
{
  const int blk = blockIdx.x, t = threadIdx.x;
  const int rsub = t >> 6;            // 0..3
  const int c0 = (t & 63) * 4;
  if (blk < 192) {
    const int n = blk * 4 + rsub;     // 0..767
    const float* W = (n < 256) ? Wq : ((n < 512) ? Wk : Wv);
    const int nn = n & 255;
    const float sc = (n < 256) ? ALPHA : 1.0f;
    #pragma unroll
    for (int c = c0; c < c0 + 4; ++c)
      Wt[(size_t)n * 256 + c] = f2bf(sc * W[(size_t)c * 256 + nn]);
  } else {
    const int d = (blk - 192) * 4 + rsub;   // 0..255
    #pragma unroll
    for (int c = c0; c < c0 + 4; ++c)
      Wot[(size_t)d * 256 + c] = f2bf(Wo[(size_t)c * 256 + d]);
  }
}

// ---------------- Kernel 1: QKV projection (per-matrix blocks) ----------------
__global__ __launch_bounds__(256, 3) void qkv_mfma(
    const float* __restrict__ query, const float* __restrict__ value,
    const unsigned short* __restrict__ Wt,
    const float* __restrict__ bq, const float* __restrict__ bk,
    const float* __restrict__ bv,
    unsigned short* __restrict__ qb, unsigned short* __restrict__ kbs,
    unsigned short* __restrict__ vts)
{
  __shared__ __align__(16) unsigned short Xs[64 * 256];   // 32 KB, swizzled

  const int t = threadIdx.x;
  const int w = t >> 6, l = t & 63, lr = l & 15, grp = l >> 4;
  const int mat = (int)(blockIdx.x % 3u);
  const int rb  = (int)(blockIdx.x / 3u);
  const long r0 = (long)rb * 64;

  const float* X = (mat == 0) ? query : value;

  {
    const int row = t >> 2;
    const int c0s = (t & 3) * 64;
    const float* xp = X + (r0 + row) * 256 + c0s;
    const int sw = (row & 7) << 3;
    #pragma unroll
    for (int g = 0; g < 8; ++g) {
      f32x4 x0 = *(const f32x4*)(xp + g * 8);
      f32x4 x1 = *(const f32x4*)(xp + g * 8 + 4);
      union { u32 wd[4]; s16x8 v; } bb;
      bb.wd[0] = cvtpk(x0[0], x0[1]);
      bb.wd[1] = cvtpk(x0[2], x0[3]);
      bb.wd[2] = cvtpk(x1[0], x1[1]);
      bb.wd[3] = cvtpk(x1[2], x1[3]);
      *(s16x8*)&Xs[(row * 256 + c0s + g * 8) ^ sw] = bb.v;
    }
  }
  __syncthreads();

  const int n0 = w * 64;                 // head w
  const int swr = (lr & 7) << 3;

  f32x4 acc[4][4] = {};

  #pragma unroll 2
  for (int k0 = 0; k0 < 256; k0 += 32) {
    s16x8 xf[4];
    #pragma unroll
    for (int mt = 0; mt < 4; ++mt)
      xf[mt] = *(const s16x8*)&Xs[((mt * 16 + lr) * 256 + k0 + grp * 8) ^ swr];
    #pragma unroll
    for (int nt = 0; nt < 4; ++nt) {
      s16x8 af = *(const s16x8*)(Wt + (size_t)(mat * 256 + n0 + nt * 16 + lr) * 256 + k0 + grp * 8);
      if (mat == 2) {
        #pragma unroll
        for (int mt = 0; mt < 4; ++mt)
          acc[mt][nt] = __builtin_amdgcn_mfma_f32_16x16x32_bf16(xf[mt], af, acc[mt][nt], 0, 0, 0);
      } else {
        #pragma unroll
        for (int mt = 0; mt < 4; ++mt)
          acc[mt][nt] = __builtin_amdgcn_mfma_f32_16x16x32_bf16(af, xf[mt], acc[mt][nt], 0, 0, 0);
      }
    }
  }

  const int b  = (int)(r0 >> 12);
  const int s0 = (int)(r0 & 4095);
  const int kt = s0 >> 6;
  const size_t base = (size_t)(b * 4 + w) * (SS * KK) + (size_t)kt * 4096;

  if (mat == 0) {
    #pragma unroll
    for (int nt = 0; nt < 4; ++nt) {
      const int nk = nt * 16 + grp * 4;
      f32x4 bias = *(const f32x4*)&bq[n0 + nk] * ALPHA;
      #pragma unroll
      for (int mt = 0; mt < 4; ++mt) {
        const int s = s0 + mt * 16 + lr;
        f32x4 o = acc[mt][nt] + bias;
        uint2 pk2; pk2.x = cvtpk(o[0], o[1]); pk2.y = cvtpk(o[2], o[3]);
        *(uint2*)&qb[((size_t)(b * 4 + w) * SS + s) * KK + nk] = pk2;
      }
    }
  } else if (mat == 1) {
    #pragma unroll
    for (int nt = 0; nt < 4; ++nt) {
      const int d0 = nt * 16 + grp * 4;
      const int cc = d0 >> 5, grpk = (d0 >> 3) & 3, jlo = d0 & 7;
      f32x4 bias = *(const f32x4*)&bk[n0 + d0];
      #pragma unroll
      for (int mt = 0; mt < 4; ++mt) {
        const int chunk = ((mt * 2 + cc) * 4 + grpk) * 16 + lr;
        f32x4 o = acc[mt][nt] + bias;
        uint2 pk2; pk2.x = cvtpk(o[0], o[1]); pk2.y = cvtpk(o[2], o[3]);
        *(uint2*)&kbs[base + chunk * 8 + jlo] = pk2;
      }
    }
  } else {
    #pragma unroll
    for (int nt = 0; nt < 4; ++nt) {
      const float bvn = bv[n0 + nt * 16 + lr];
      #pragma unroll
      for (int mt = 0; mt < 4; ++mt) {
        const int cb = (nt * 2 + (mt >> 1)) * 64 + grp * 16 + lr;
        f32x4 o = acc[mt][nt] + bvn;
        uint2 pk2; pk2.x = cvtpk(o[0], o[1]); pk2.y = cvtpk(o[2], o[3]);
        *(uint2*)&vts[base + (size_t)cb * 8 + (mt & 1) * 4] = pk2;
      }
    }
  }
}

// ---------------- Kernel 2: causal flash attention (kv-half waves, in-block merge) ----------------
// 1024 blocks x 256 thr, 4 blocks/CU. Waves = (qg) x (kh): each wave computes
// its 32-kv half. At epilogues, kh=1 waves dump cacc into the freed Kl/Vl[cur]
// (lane-consecutive, conflict-free) and kh=0 waves write MERGED slots:
// ns0 (all rows: light final / heavy partial) + ns2 (heavy partial), lb0/lb2.
__global__ __launch_bounds__(256, 4) void attn(
    const unsigned short* __restrict__ qb,
    const unsigned short* __restrict__ kbs,
    const unsigned short* __restrict__ vts,
    unsigned short* __restrict__ ns0, unsigned short* __restrict__ ns2,
    float* __restrict__ lb0, float* __restrict__ lb2)
{
  __shared__ __align__(16) unsigned short Kl[2][4096];
  __shared__ __align__(16) unsigned short Vl[2][4096];
  __shared__ float lred[2][2][16];

  const int t = threadIdx.x;
  const int w = t >> 6, l = t & 63, lr = l & 15, grp = l >> 4;
  const int qg = w >> 1, kh = w & 1;

  const int i    = blockIdx.x;
  const int bh   = i & 15;
  const int pr   = (i >> 4) & 31;
  const int role = (i >> 9) & 1;
  const int b = bh >> 2, h = bh & 3;

  const unsigned short* kbase = kbs + (size_t)bh * (SS * KK);
  const unsigned short* vbase = vts + (size_t)bh * (SS * KK);
  const unsigned short* qpb   = qb  + (size_t)bh * (SS * KK);

  int sup = (role == 0) ? pr : (63 - pr);
  const int nsteps = 33 - role;

  s16x8 qf[2][2];
  #pragma unroll
  for (int q2 = 0; q2 < 2; ++q2) {
    const unsigned short* qp = qpb + (size_t)(sup * 64 + qg * 32 + q2 * 16 + lr) * KK;
    qf[q2][0] = *(const s16x8*)(qp + grp * 8);
    qf[q2][1] = *(const s16x8*)(qp + 32 + grp * 8);
  }

  s16x8 ones;
  #pragma unroll
  for (int e = 0; e < 8; ++e) ones[e] = (short)0x3F80;   // bf16 1.0
  const f32x4 minit = {-16.f, -16.f, -16.f, -16.f};

  f32x4 cacc[2][4] = {};
  f32x4 lacc[2] = {};

  const int off0 = (w * 64 + l) * 8;
  const int off1 = ((4 + w) * 64 + l) * 8;

  auto ktfor = [&](int s) {
    return (role == 0) ? ((s <= pr) ? s : (s - (pr + 1))) : (32 - pr + s);
  };
  auto stage = [&](int kt, int bi) {
    const unsigned short* ks = kbase + (size_t)kt * 4096;
    const unsigned short* vs = vbase + (size_t)kt * 4096;
    gl_lds16(ks + off0, &Kl[bi][w * 512]);
    gl_lds16(ks + off1, &Kl[bi][(4 + w) * 512]);
    gl_lds16(vs + off0, &Vl[bi][w * 512]);
    gl_lds16(vs + off1, &Vl[bi][(4 + w) * 512]);
  };

  // kh-merge: kh=1 writes its cacc/lacc into freed Kl/Vl[cur]; kh=0 adds.
  auto merge_kh = [&](int cur) {
    float* mb0 = (float*)&Kl[cur][0];   // q2 = 0
    float* mb1 = (float*)&Vl[cur][0];   // q2 = 1
    if (kh == 1) {
      #pragma unroll
      for (int m2 = 0; m2 < 4; ++m2)
        #pragma unroll
        for (int e = 0; e < 4; ++e) {
          mb0[(m2 * 4 + e) * 128 + qg * 64 + l] = cacc[0][m2][e];
          mb1[(m2 * 4 + e) * 128 + qg * 64 + l] = cacc[1][m2][e];
        }
      if (grp == 0) { lred[qg][0][lr] = lacc[0][0]; lred[qg][1][lr] = lacc[1][0]; }
    }
    __syncthreads();
    if (kh == 0) {
      #pragma unroll
      for (int m2 = 0; m2 < 4; ++m2)
        #pragma unroll
        for (int e = 0; e < 4; ++e) {
          cacc[0][m2][e] += mb0[(m2 * 4 + e) * 128 + qg * 64 + l];
          cacc[1][m2][e] += mb1[(m2 * 4 + e) * 128 + qg * 64 + l];
        }
    }
  };

  stage(ktfor(0), 0);
  __syncthreads();

  for (int ss = 0; ss < nsteps; ++ss) {
    const int cur = ss & 1;
    if (ss + 1 < nsteps) stage(ktfor(ss + 1), cur ^ 1);

    const int kt = ktfor(ss);
    const unsigned short* Kb = &Kl[cur][0];
    const unsigned short* Vb = &Vl[cur][0];

    s16x8 kf[4];
    #pragma unroll
    for (int j = 0; j < 4; ++j)
      kf[j] = *(const s16x8*)&Kb[(((kh * 4 + j) * 4 + grp) * 16 + lr) * 8];

    __builtin_amdgcn_s_setprio(1);
    f32x4 sc[2][2];
    #pragma unroll
    for (int q2 = 0; q2 < 2; ++q2) {
      #pragma unroll
      for (int tt = 0; tt < 2; ++tt) {
        f32x4 a = __builtin_amdgcn_mfma_f32_16x16x32_bf16(kf[tt * 2 + 0], qf[q2][0], minit, 0, 0, 0);
        a = __builtin_amdgcn_mfma_f32_16x16x32_bf16(kf[tt * 2 + 1], qf[q2][1], a, 0, 0, 0);
        sc[q2][tt] = a;
      }
    }
    __builtin_amdgcn_s_setprio(0);

    if (kt == sup) {
      #pragma unroll
      for (int q2 = 0; q2 < 2; ++q2) {
        const int qloc = qg * 32 + q2 * 16 + lr;
        #pragma unroll
        for (int tt = 0; tt < 2; ++tt)
          #pragma unroll
          for (int e = 0; e < 4; ++e)
            if (((kh * 2 + tt) * 16 + grp * 4 + e) > qloc) sc[q2][tt][e] += -1.0e9f;
      }
    }

    #pragma unroll
    for (int q2 = 0; q2 < 2; ++q2)
      #pragma unroll
      for (int tt = 0; tt < 2; ++tt)
        #pragma unroll
        for (int e = 0; e < 4; ++e)
          sc[q2][tt][e] = fexp2(sc[q2][tt][e]);

    s16x8 pf[2];
    #pragma unroll
    for (int q2 = 0; q2 < 2; ++q2) {
      union { u32 wd[4]; s16x8 v; } pu;
      pu.wd[0] = cvtpk(sc[q2][0][0], sc[q2][0][1]);
      pu.wd[1] = cvtpk(sc[q2][0][2], sc[q2][0][3]);
      pu.wd[2] = cvtpk(sc[q2][1][0], sc[q2][1][1]);
      pu.wd[3] = cvtpk(sc[q2][1][2], sc[q2][1][3]);
      pf[q2] = pu.v;
    }

    __builtin_amdgcn_s_setprio(1);
    #pragma unroll
    for (int m2 = 0; m2 < 4; ++m2) {
      s16x8 vfr = *(const s16x8*)&Vb[((m2 * 2 + kh) * 64 + l) * 8];
      cacc[0][m2] = __builtin_amdgcn_mfma_f32_16x16x32_bf16(vfr, pf[0], cacc[0][m2], 0, 0, 0);
      cacc[1][m2] = __builtin_amdgcn_mfma_f32_16x16x32_bf16(vfr, pf[1], cacc[1][m2], 0, 0, 0);
    }
    lacc[0] = __builtin_amdgcn_mfma_f32_16x16x32_bf16(ones, pf[0], lacc[0], 0, 0, 0);
    lacc[1] = __builtin_amdgcn_mfma_f32_16x16x32_bf16(ones, pf[1], lacc[1], 0, 0, 0);
    __builtin_amdgcn_s_setprio(0);

    // role0 phase switch: merge kh partials, write FINAL light rows to ns0
    if (role == 0 && ss == pr) {
      __syncthreads();                  // all waves done reading Kl/Vl[cur]
      merge_kh(cur);
      if (kh == 0) {
        #pragma unroll
        for (int q2 = 0; q2 < 2; ++q2) {
          const int rowg = sup * 64 + qg * 32 + q2 * 16 + lr;
          unsigned short* np_ = ns0 + ((size_t)((b << 12) + rowg)) * 256 + h * 64;
          #pragma unroll
          for (int m2 = 0; m2 < 4; ++m2) {
            uint2 pk2; pk2.x = cvtpk(cacc[q2][m2][0], cacc[q2][m2][1]);
            pk2.y = cvtpk(cacc[q2][m2][2], cacc[q2][m2][3]);
            *(uint2*)&np_[m2 * 16 + grp * 4] = pk2;
          }
          if (grp == 0) lb0[(bh << 12) + rowg] = lacc[q2][0] + lred[qg][q2][lr];
        }
      }
      #pragma unroll
      for (int q2 = 0; q2 < 2; ++q2) {
        cacc[q2][0] = cacc[q2][1] = cacc[q2][2] = cacc[q2][3] = (f32x4){0.f, 0.f, 0.f, 0.f};
        lacc[q2] = (f32x4){0.f, 0.f, 0.f, 0.f};
      }
      sup = 63 - pr;
      #pragma unroll
      for (int q2 = 0; q2 < 2; ++q2) {
        const unsigned short* qp = qpb + (size_t)(sup * 64 + qg * 32 + q2 * 16 + lr) * KK;
        qf[q2][0] = *(const s16x8*)(qp + grp * 8);
        qf[q2][1] = *(const s16x8*)(qp + 32 + grp * 8);
      }
    }
    __syncthreads();
  }

  // final epilogue: merge kh, then role0 -> ns0 (heavy partial), role1 -> ns2
  merge_kh((nsteps - 1) & 1);
  if (kh == 0) {
    if (role == 0) {
      #pragma unroll
      for (int q2 = 0; q2 < 2; ++q2) {
        const int rowg = sup * 64 + qg * 32 + q2 * 16 + lr;
        unsigned short* np_ = ns0 + ((size_t)((b << 12) + rowg)) * 256 + h * 64;
        #pragma unroll
        for (int m2 = 0; m2 < 4; ++m2) {
          uint2 pk2; pk2.x = cvtpk(cacc[q2][m2][0], cacc[q2][m2][1]);
          pk2.y = cvtpk(cacc[q2][m2][2], cacc[q2][m2][3]);
          *(uint2*)&np_[m2 * 16 + grp * 4] = pk2;
        }
        if (grp == 0) lb0[(bh << 12) + rowg] = lacc[q2][0] + lred[qg][q2][lr];
      }
    } else {
      #pragma unroll
      for (int q2 = 0; q2 < 2; ++q2) {
        const int rowg = sup * 64 + qg * 32 + q2 * 16 + lr;   // >= 2048
        unsigned short* np_ = ns2 + ((size_t)((b << 11) + (rowg - 2048))) * 256 + h * 64;
        #pragma unroll
        for (int m2 = 0; m2 < 4; ++m2) {
          uint2 pk2; pk2.x = cvtpk(cacc[q2][m2][0], cacc[q2][m2][1]);
          pk2.y = cvtpk(cacc[q2][m2][2], cacc[q2][m2][3]);
          *(uint2*)&np_[m2 * 16 + grp * 4] = pk2;
        }
        if (grp == 0) lb2[(bh << 11) + (rowg - 2048)] = lacc[q2][0] + lred[qg][q2][lr];
      }
    }
  }
}

// ---------------- Kernel 3: output projection + residual + LayerNorm (MFMA) ----------------
__global__ __launch_bounds__(256, 4) void oproj_ln(
    const unsigned short* __restrict__ ns0, const unsigned short* __restrict__ ns2,
    const float* __restrict__ lb0, const float* __restrict__ lb2,
    const unsigned short* __restrict__ Wot,
    const float* __restrict__ bo, const float* __restrict__ query,
    const float* __restrict__ gamma, const float* __restrict__ beta,
    float* __restrict__ out)
{
  __shared__ __align__(16) float redS[32][4];
  __shared__ __align__(16) float redQ[32][4];

  const int t = threadIdx.x;
  const int w = t >> 6, l = t & 63, lr = l & 15, grp = l >> 4;
  const long r0 = (long)blockIdx.x * 32;
  const int n0c = w * 64;
  const int b = (int)(r0 >> 12);
  const bool heavy = ((r0 >> 11) & 1) != 0;

  float invl[2][4];
  #pragma unroll
  for (int mt = 0; mt < 2; ++mt) {
    const int grow = (int)r0 + mt * 16 + lr;
    #pragma unroll
    for (int h = 0; h < 4; ++h) {
      float lv = lb0[((b * 4 + h) << 12) + (grow & 4095)];
      if (heavy) lv += lb2[((b * 4 + h) << 11) + (grow & 2047)];
      invl[mt][h] = 1.0f / lv;
    }
  }

  f32x4 acc[2][4] = {};

  #pragma unroll
  for (int k0 = 0; k0 < 256; k0 += 32) {
    s16x8 bfr[2];
    #pragma unroll
    for (int mt = 0; mt < 2; ++mt) {
      const int grow = (int)r0 + mt * 16 + lr;
      const int c = k0 + grp * 8;
      f32x4 a0 = {0.f, 0.f, 0.f, 0.f}, a1 = {0.f, 0.f, 0.f, 0.f};
      acc8(ns0 + (size_t)grow * 256 + c, a0, a1);
      if (heavy)
        acc8(ns2 + ((size_t)((b << 11) + (grow & 2047))) * 256 + c, a0, a1);
      const float iv = invl[mt][k0 >> 6];
      a0 *= iv; a1 *= iv;
      union { u32 wd[4]; s16x8 v; } bb;
      bb.wd[0] = cvtpk(a0[0], a0[1]);
      bb.wd[1] = cvtpk(a0[2], a0[3]);
      bb.wd[2] = cvtpk(a1[0], a1[1]);
      bb.wd[3] = cvtpk(a1[2], a1[3]);
      bfr[mt] = bb.v;
    }
    #pragma unroll
    for (int nt = 0; nt < 4; ++nt) {
      s16x8 af = *(const s16x8*)(Wot + (size_t)(n0c + nt * 16 + lr) * 256 + k0 + grp * 8);
      acc[0][nt] = __builtin_amdgcn_mfma_f32_16x16x32_bf16(af, bfr[0], acc[0][nt], 0, 0, 0);
      acc[1][nt] = __builtin_amdgcn_mfma_f32_16x16x32_bf16(af, bfr[1], acc[1][nt], 0, 0, 0);
    }
  }

  float sm[2] = {0.f, 0.f}, sq[2] = {0.f, 0.f};
  #pragma unroll
  for (int mt = 0; mt < 2; ++mt) {
    const long s = r0 + mt * 16 + lr;
    #pragma unroll
    for (int nt = 0; nt < 4; ++nt) {
      const int n = n0c + nt * 16 + grp * 4;
      f32x4 v = acc[mt][nt] + *(const f32x4*)&bo[n] + *(const f32x4*)&query[s * 256 + n];
      acc[mt][nt] = v;
      sm[mt] += v[0] + v[1] + v[2] + v[3];
      sq[mt] += v[0]*v[0] + v[1]*v[1] + v[2]*v[2] + v[3]*v[3];
    }
    sm[mt] += __shfl_xor(sm[mt], 16); sm[mt] += __shfl_xor(sm[mt], 32);
    sq[mt] += __shfl_xor(sq[mt], 16); sq[mt] += __shfl_xor(sq[mt], 32);
  }
  if (grp == 0) {
    redS[0 * 16 + lr][w] = sm[0]; redQ[0 * 16 + lr][w] = sq[0];
    redS[1 * 16 + lr][w] = sm[1]; redQ[1 * 16 + lr][w] = sq[1];
  }
  __syncthreads();

  #pragma unroll
  for (int mt = 0; mt < 2; ++mt) {
    f32x4 s4 = *(const f32x4*)&redS[mt * 16 + lr][0];
    f32x4 q4 = *(const f32x4*)&redQ[mt * 16 + lr][0];
    const float tot = s4[0] + s4[1] + s4[2] + s4[3];
    const float tq  = q4[0] + q4[1] + q4[2] + q4[3];
    const float mu  = tot * 0.00390625f;
    const float var = tq * 0.00390625f - mu * mu;
    const float rs  = rsqrtf(var + 1.0e-3f);
    const long s = r0 + mt * 16 + lr;
    #pragma unroll
    for (int nt = 0; nt < 4; ++nt) {
      const int n = n0c + nt * 16 + grp * 4;
      f32x4 g = *(const f32x4*)&gamma[n];
      f32x4 bt = *(const f32x4*)&beta[n];
      f32x4 o = (acc[mt][nt] - mu) * rs * g + bt;
      *(f32x4*)&out[s * 256 + n] = o;
    }
  }
}

extern "C" void kernel_launch(void* const* d_in, const int* in_sizes, int n_in,
                              void* d_out, int out_size, void* d_ws, size_t ws_size,
                              hipStream_t stream) {
  const float* query = (const float*)d_in[0];
  const float* value = (const float*)d_in[1];
  const float* Wq    = (const float*)d_in[2];
  const float* bq    = (const float*)d_in[3];
  const float* Wk    = (const float*)d_in[4];
  const float* bk    = (const float*)d_in[5];
  const float* Wv    = (const float*)d_in[6];
  const float* bv    = (const float*)d_in[7];
  const float* Wo    = (const float*)d_in[8];
  const float* bo    = (const float*)d_in[9];
  const float* gamma = (const float*)d_in[10];
  const float* beta  = (const float*)d_in[11];
  float* out = (float*)d_out;

  char* ws = (char*)d_ws;
  unsigned short* qb  = (unsigned short*)ws;                          //  8 MiB bf16 [bh][s][dk]
  unsigned short* kbs = (unsigned short*)(ws + ((size_t)8  << 20));   //  8 MiB bf16 chunked K
  unsigned short* vts = (unsigned short*)(ws + ((size_t)16 << 20));   //  8 MiB bf16 chunked V^T
  unsigned short* ns0 = (unsigned short*)(ws + ((size_t)24 << 20));   //  8 MiB bf16 [b*4096][256]
  unsigned short* ns2 = (unsigned short*)(ws + ((size_t)32 << 20));   //  4 MiB bf16 [b*2048][256]
  float* lb0 = (float*)(ws + ((size_t)36 << 20));                     // 256 KiB f32 [16][4096]
  float* lb2 = (float*)(ws + ((size_t)36 << 20) + ((size_t)256 << 10)); // 128 KiB f32 [16][2048]
  unsigned short* Wt  = (unsigned short*)(ws + ((size_t)36 << 20) + ((size_t)512 << 10)); // 384 KiB
  unsigned short* Wot = Wt + (size_t)768 * 256;                       // 128 KiB

  wprep<<<256, 256, 0, stream>>>(Wq, Wk, Wv, Wo, Wt, Wot);
  qkv_mfma<<<768, 256, 0, stream>>>(query, value, Wt, bq, bk, bv, qb, kbs, vts);
  attn<<<1024, 256, 0, stream>>>(qb, kbs, vts, ns0, ns2, lb0, lb2);
  oproj_ln<<<512, 256, 0, stream>>>(ns0, ns2, lb0, lb2, Wot, bo, query, gamma, beta, out);
}

// Round 18
// 100.808 us; speedup vs baseline: 1.0552x; 1.0029x over previous
//
#include <hip/hip_runtime.h>
#include <hip/hip_bf16.h>
#include <stdint.h>

#define SS 4096
#define DD 256
#define HH 4
#define KK 64
#define ALPHA 0.18033688011112042f  // 0.125 * log2(e)

typedef float f32x4 __attribute__((ext_vector_type(4)));
typedef short s16x8 __attribute__((ext_vector_type(8)));
typedef unsigned int u32;

__device__ __forceinline__ unsigned short f2bf(float x) {
  union { float f; unsigned u; } v; v.f = x;
  unsigned r = v.u + 0x7fffu + ((v.u >> 16) & 1u);
  return (unsigned short)(r >> 16);
}

__device__ __forceinline__ u32 cvtpk(float lo, float hi) {
  u32 r;
  asm("v_cvt_pk_bf16_f32 %0, %1, %2" : "=v"(r) : "v"(lo), "v"(hi));
  return r;
}

// hardware 2^x via compiler intrinsic (hazard-safe, single v_exp_f32)
#define fexp2(x) __builtin_amdgcn_exp2f(x)

__device__ __forceinline__ void gl_lds16(const unsigned short* g, unsigned short* l) {
  __builtin_amdgcn_global_load_lds(
      (const __attribute__((address_space(1))) u32*)g,
      (__attribute__((address_space(3))) u32*)l, 16, 0, 0);
}

// accumulate 8 bf16 (as shorts) into two f32x4
__device__ __forceinline__ void acc8(const unsigned short* p, f32x4& a0, f32x4& a1) {
  s16x8 v = *(const s16x8*)p;
  union { u32 u; float f; } c;
  #pragma unroll
  for (int j = 0; j < 4; ++j) { c.u = ((u32)(unsigned short)v[j]) << 16; a0[j] += c.f; }
  #pragma unroll
  for (int j = 0; j < 4; ++j) { c.u = ((u32)(unsigned short)v[4 + j]) << 16; a1[j] += c.f; }
}

// ---------------- Kernel 0: weight prep (tiled LDS transpose, coalesced) ----------------
// 64 blocks = mat(4: Wq,Wk,Wv,Wo) x ti(4) x tj(4), 64x64 tiles.
// dst[i][j] = sc * src[j][i]; loads coalesced f32x4, stores coalesced 16B.
__global__ void wprep(const float* __restrict__ Wq, const float* __restrict__ Wk,
                      const float* __restrict__ Wv, const float* __restrict__ Wo,
                      unsigned short* __restrict__ Wt, unsigned short* __restrict__ Wot)
{
  __shared__ unsigned short L[64][72];
  const int blk = blockIdx.x;
  const int mat = blk >> 4;
  const int ti = (blk >> 2) & 3;
  const int tj = blk & 3;
  const int t = threadIdx.x;
  const float sc = (mat == 0) ? ALPHA : 1.0f;
  const float* src = (mat == 0) ? Wq : (mat == 1) ? Wk : (mat == 2) ? Wv : Wo;
  unsigned short* dst = (mat < 3) ? (Wt + (size_t)mat * 256 * 256) : Wot;
  const int i0 = ti * 64, j0 = tj * 64;

  {
    const int jj = t >> 4;            // 0..15, 4 passes
    const int ii = (t & 15) * 4;
    #pragma unroll
    for (int p = 0; p < 4; ++p) {
      f32x4 v = *(const f32x4*)&src[(size_t)(j0 + jj + p * 16) * 256 + i0 + ii];
      uint2 pk; pk.x = cvtpk(sc * v[0], sc * v[1]); pk.y = cvtpk(sc * v[2], sc * v[3]);
      *(uint2*)&L[jj + p * 16][ii] = pk;
    }
  }
  __syncthreads();

  const int i = i0 + (t >> 2);
  const int jb = (t & 3) * 16;
  union { unsigned short u[16]; s16x8 v[2]; } pk;
  #pragma unroll
  for (int s = 0; s < 16; ++s) pk.u[s] = L[jb + s][t >> 2];
  *(s16x8*)&dst[(size_t)i * 256 + j0 + jb] = pk.v[0];
  *(s16x8*)&dst[(size_t)i * 256 + j0 + jb + 8] = pk.v[1];
}

// ---------------- Kernel 1: QKV projection (per-matrix blocks) ----------------
__global__ __launch_bounds__(256, 3) void qkv_mfma(
    const float* __restrict__ query, const float* __restrict__ value,
    const unsigned short* __restrict__ Wt,
    const float* __restrict__ bq, const float* __restrict__ bk,
    const float* __restrict__ bv,
    unsigned short* __restrict__ qb, unsigned short* __restrict__ kbs,
    unsigned short* __restrict__ vts)
{
  __shared__ __align__(16) unsigned short Xs[64 * 256];   // 32 KB, swizzled

  const int t = threadIdx.x;
  const int w = t >> 6, l = t & 63, lr = l & 15, grp = l >> 4;
  const int mat = (int)(blockIdx.x % 3u);
  const int rb  = (int)(blockIdx.x / 3u);
  const long r0 = (long)rb * 64;

  const float* X = (mat == 0) ? query : value;

  {
    const int row = t >> 2;
    const int c0s = (t & 3) * 64;
    const float* xp = X + (r0 + row) * 256 + c0s;
    const int sw = (row & 7) << 3;
    #pragma unroll
    for (int g = 0; g < 8; ++g) {
      f32x4 x0 = *(const f32x4*)(xp + g * 8);
      f32x4 x1 = *(const f32x4*)(xp + g * 8 + 4);
      union { u32 wd[4]; s16x8 v; } bb;
      bb.wd[0] = cvtpk(x0[0], x0[1]);
      bb.wd[1] = cvtpk(x0[2], x0[3]);
      bb.wd[2] = cvtpk(x1[0], x1[1]);
      bb.wd[3] = cvtpk(x1[2], x1[3]);
      *(s16x8*)&Xs[(row * 256 + c0s + g * 8) ^ sw] = bb.v;
    }
  }
  __syncthreads();

  const int n0 = w * 64;                 // head w
  const int swr = (lr & 7) << 3;

  f32x4 acc[4][4] = {};

  #pragma unroll 2
  for (int k0 = 0; k0 < 256; k0 += 32) {
    s16x8 xf[4];
    #pragma unroll
    for (int mt = 0; mt < 4; ++mt)
      xf[mt] = *(const s16x8*)&Xs[((mt * 16 + lr) * 256 + k0 + grp * 8) ^ swr];
    #pragma unroll
    for (int nt = 0; nt < 4; ++nt) {
      s16x8 af = *(const s16x8*)(Wt + (size_t)(mat * 256 + n0 + nt * 16 + lr) * 256 + k0 + grp * 8);
      if (mat == 2) {
        #pragma unroll
        for (int mt = 0; mt < 4; ++mt)
          acc[mt][nt] = __builtin_amdgcn_mfma_f32_16x16x32_bf16(xf[mt], af, acc[mt][nt], 0, 0, 0);
      } else {
        #pragma unroll
        for (int mt = 0; mt < 4; ++mt)
          acc[mt][nt] = __builtin_amdgcn_mfma_f32_16x16x32_bf16(af, xf[mt], acc[mt][nt], 0, 0, 0);
      }
    }
  }

  const int b  = (int)(r0 >> 12);
  const int s0 = (int)(r0 & 4095);
  const int kt = s0 >> 6;
  const size_t base = (size_t)(b * 4 + w) * (SS * KK) + (size_t)kt * 4096;

  if (mat == 0) {
    #pragma unroll
    for (int nt = 0; nt < 4; ++nt) {
      const int nk = nt * 16 + grp * 4;
      f32x4 bias = *(const f32x4*)&bq[n0 + nk] * ALPHA;
      #pragma unroll
      for (int mt = 0; mt < 4; ++mt) {
        const int s = s0 + mt * 16 + lr;
        f32x4 o = acc[mt][nt] + bias;
        uint2 pk2; pk2.x = cvtpk(o[0], o[1]); pk2.y = cvtpk(o[2], o[3]);
        *(uint2*)&qb[((size_t)(b * 4 + w) * SS + s) * KK + nk] = pk2;
      }
    }
  } else if (mat == 1) {
    #pragma unroll
    for (int nt = 0; nt < 4; ++nt) {
      const int d0 = nt * 16 + grp * 4;
      const int cc = d0 >> 5, grpk = (d0 >> 3) & 3, jlo = d0 & 7;
      f32x4 bias = *(const f32x4*)&bk[n0 + d0];
      #pragma unroll
      for (int mt = 0; mt < 4; ++mt) {
        const int chunk = ((mt * 2 + cc) * 4 + grpk) * 16 + lr;
        f32x4 o = acc[mt][nt] + bias;
        uint2 pk2; pk2.x = cvtpk(o[0], o[1]); pk2.y = cvtpk(o[2], o[3]);
        *(uint2*)&kbs[base + chunk * 8 + jlo] = pk2;
      }
    }
  } else {
    #pragma unroll
    for (int nt = 0; nt < 4; ++nt) {
      const float bvn = bv[n0 + nt * 16 + lr];
      #pragma unroll
      for (int mt = 0; mt < 4; ++mt) {
        const int cb = (nt * 2 + (mt >> 1)) * 64 + grp * 16 + lr;
        f32x4 o = acc[mt][nt] + bvn;
        uint2 pk2; pk2.x = cvtpk(o[0], o[1]); pk2.y = cvtpk(o[2], o[3]);
        *(uint2*)&vts[base + (size_t)cb * 8 + (mt & 1) * 4] = pk2;
      }
    }
  }
}

// ---------------- Kernel 2: causal flash attention (kv-half waves, in-block merge) ----------------
__global__ __launch_bounds__(256, 4) void attn(
    const unsigned short* __restrict__ qb,
    const unsigned short* __restrict__ kbs,
    const unsigned short* __restrict__ vts,
    unsigned short* __restrict__ ns0, unsigned short* __restrict__ ns2,
    float* __restrict__ lb0, float* __restrict__ lb2)
{
  __shared__ __align__(16) unsigned short Kl[2][4096];
  __shared__ __align__(16) unsigned short Vl[2][4096];
  __shared__ float lred[2][2][16];

  const int t = threadIdx.x;
  const int w = t >> 6, l = t & 63, lr = l & 15, grp = l >> 4;
  const int qg = w >> 1, kh = w & 1;

  const int i    = blockIdx.x;
  const int bh   = i & 15;
  const int pr   = (i >> 4) & 31;
  const int role = (i >> 9) & 1;
  const int b = bh >> 2, h = bh & 3;

  const unsigned short* kbase = kbs + (size_t)bh * (SS * KK);
  const unsigned short* vbase = vts + (size_t)bh * (SS * KK);
  const unsigned short* qpb   = qb  + (size_t)bh * (SS * KK);

  int sup = (role == 0) ? pr : (63 - pr);
  const int nsteps = 33 - role;

  s16x8 qf[2][2];
  #pragma unroll
  for (int q2 = 0; q2 < 2; ++q2) {
    const unsigned short* qp = qpb + (size_t)(sup * 64 + qg * 32 + q2 * 16 + lr) * KK;
    qf[q2][0] = *(const s16x8*)(qp + grp * 8);
    qf[q2][1] = *(const s16x8*)(qp + 32 + grp * 8);
  }

  s16x8 ones;
  #pragma unroll
  for (int e = 0; e < 8; ++e) ones[e] = (short)0x3F80;   // bf16 1.0
  const f32x4 minit = {-16.f, -16.f, -16.f, -16.f};

  f32x4 cacc[2][4] = {};
  f32x4 lacc[2] = {};

  const int off0 = (w * 64 + l) * 8;
  const int off1 = ((4 + w) * 64 + l) * 8;

  auto ktfor = [&](int s) {
    return (role == 0) ? ((s <= pr) ? s : (s - (pr + 1))) : (32 - pr + s);
  };
  auto stage = [&](int kt, int bi) {
    const unsigned short* ks = kbase + (size_t)kt * 4096;
    const unsigned short* vs = vbase + (size_t)kt * 4096;
    gl_lds16(ks + off0, &Kl[bi][w * 512]);
    gl_lds16(ks + off1, &Kl[bi][(4 + w) * 512]);
    gl_lds16(vs + off0, &Vl[bi][w * 512]);
    gl_lds16(vs + off1, &Vl[bi][(4 + w) * 512]);
  };

  // kh-merge: kh=1 writes its cacc/lacc into freed Kl/Vl[cur]; kh=0 adds.
  auto merge_kh = [&](int cur) {
    float* mb0 = (float*)&Kl[cur][0];   // q2 = 0
    float* mb1 = (float*)&Vl[cur][0];   // q2 = 1
    if (kh == 1) {
      #pragma unroll
      for (int m2 = 0; m2 < 4; ++m2)
        #pragma unroll
        for (int e = 0; e < 4; ++e) {
          mb0[(m2 * 4 + e) * 128 + qg * 64 + l] = cacc[0][m2][e];
          mb1[(m2 * 4 + e) * 128 + qg * 64 + l] = cacc[1][m2][e];
        }
      if (grp == 0) { lred[qg][0][lr] = lacc[0][0]; lred[qg][1][lr] = lacc[1][0]; }
    }
    __syncthreads();
    if (kh == 0) {
      #pragma unroll
      for (int m2 = 0; m2 < 4; ++m2)
        #pragma unroll
        for (int e = 0; e < 4; ++e) {
          cacc[0][m2][e] += mb0[(m2 * 4 + e) * 128 + qg * 64 + l];
          cacc[1][m2][e] += mb1[(m2 * 4 + e) * 128 + qg * 64 + l];
        }
    }
  };

  stage(ktfor(0), 0);
  __syncthreads();

  for (int ss = 0; ss < nsteps; ++ss) {
    const int cur = ss & 1;
    if (ss + 1 < nsteps) stage(ktfor(ss + 1), cur ^ 1);

    const int kt = ktfor(ss);
    const unsigned short* Kb = &Kl[cur][0];
    const unsigned short* Vb = &Vl[cur][0];

    s16x8 kf[4];
    #pragma unroll
    for (int j = 0; j < 4; ++j)
      kf[j] = *(const s16x8*)&Kb[(((kh * 4 + j) * 4 + grp) * 16 + lr) * 8];

    __builtin_amdgcn_s_setprio(1);
    f32x4 sc[2][2];
    #pragma unroll
    for (int q2 = 0; q2 < 2; ++q2) {
      #pragma unroll
      for (int tt = 0; tt < 2; ++tt) {
        f32x4 a = __builtin_amdgcn_mfma_f32_16x16x32_bf16(kf[tt * 2 + 0], qf[q2][0], minit, 0, 0, 0);
        a = __builtin_amdgcn_mfma_f32_16x16x32_bf16(kf[tt * 2 + 1], qf[q2][1], a, 0, 0, 0);
        sc[q2][tt] = a;
      }
    }
    __builtin_amdgcn_s_setprio(0);

    if (kt == sup) {
      #pragma unroll
      for (int q2 = 0; q2 < 2; ++q2) {
        const int qloc = qg * 32 + q2 * 16 + lr;
        #pragma unroll
        for (int tt = 0; tt < 2; ++tt)
          #pragma unroll
          for (int e = 0; e < 4; ++e)
            if (((kh * 2 + tt) * 16 + grp * 4 + e) > qloc) sc[q2][tt][e] += -1.0e9f;
      }
    }

    #pragma unroll
    for (int q2 = 0; q2 < 2; ++q2)
      #pragma unroll
      for (int tt = 0; tt < 2; ++tt)
        #pragma unroll
        for (int e = 0; e < 4; ++e)
          sc[q2][tt][e] = fexp2(sc[q2][tt][e]);

    s16x8 pf[2];
    #pragma unroll
    for (int q2 = 0; q2 < 2; ++q2) {
      union { u32 wd[4]; s16x8 v; } pu;
      pu.wd[0] = cvtpk(sc[q2][0][0], sc[q2][0][1]);
      pu.wd[1] = cvtpk(sc[q2][0][2], sc[q2][0][3]);
      pu.wd[2] = cvtpk(sc[q2][1][0], sc[q2][1][1]);
      pu.wd[3] = cvtpk(sc[q2][1][2], sc[q2][1][3]);
      pf[q2] = pu.v;
    }

    __builtin_amdgcn_s_setprio(1);
    #pragma unroll
    for (int m2 = 0; m2 < 4; ++m2) {
      s16x8 vfr = *(const s16x8*)&Vb[((m2 * 2 + kh) * 64 + l) * 8];
      cacc[0][m2] = __builtin_amdgcn_mfma_f32_16x16x32_bf16(vfr, pf[0], cacc[0][m2], 0, 0, 0);
      cacc[1][m2] = __builtin_amdgcn_mfma_f32_16x16x32_bf16(vfr, pf[1], cacc[1][m2], 0, 0, 0);
    }
    lacc[0] = __builtin_amdgcn_mfma_f32_16x16x32_bf16(ones, pf[0], lacc[0], 0, 0, 0);
    lacc[1] = __builtin_amdgcn_mfma_f32_16x16x32_bf16(ones, pf[1], lacc[1], 0, 0, 0);
    __builtin_amdgcn_s_setprio(0);

    // role0 phase switch: merge kh partials, write FINAL light rows to ns0
    if (role == 0 && ss == pr) {
      __syncthreads();                  // all waves done reading Kl/Vl[cur]
      merge_kh(cur);
      if (kh == 0) {
        #pragma unroll
        for (int q2 = 0; q2 < 2; ++q2) {
          const int rowg = sup * 64 + qg * 32 + q2 * 16 + lr;
          unsigned short* np_ = ns0 + ((size_t)((b << 12) + rowg)) * 256 + h * 64;
          #pragma unroll
          for (int m2 = 0; m2 < 4; ++m2) {
            uint2 pk2; pk2.x = cvtpk(cacc[q2][m2][0], cacc[q2][m2][1]);
            pk2.y = cvtpk(cacc[q2][m2][2], cacc[q2][m2][3]);
            *(uint2*)&np_[m2 * 16 + grp * 4] = pk2;
          }
          if (grp == 0) lb0[(bh << 12) + rowg] = lacc[q2][0] + lred[qg][q2][lr];
        }
      }
      #pragma unroll
      for (int q2 = 0; q2 < 2; ++q2) {
        cacc[q2][0] = cacc[q2][1] = cacc[q2][2] = cacc[q2][3] = (f32x4){0.f, 0.f, 0.f, 0.f};
        lacc[q2] = (f32x4){0.f, 0.f, 0.f, 0.f};
      }
      sup = 63 - pr;
      #pragma unroll
      for (int q2 = 0; q2 < 2; ++q2) {
        const unsigned short* qp = qpb + (size_t)(sup * 64 + qg * 32 + q2 * 16 + lr) * KK;
        qf[q2][0] = *(const s16x8*)(qp + grp * 8);
        qf[q2][1] = *(const s16x8*)(qp + 32 + grp * 8);
      }
    }
    __syncthreads();
  }

  // final epilogue: merge kh, then role0 -> ns0 (heavy partial), role1 -> ns2
  merge_kh((nsteps - 1) & 1);
  if (kh == 0) {
    if (role == 0) {
      #pragma unroll
      for (int q2 = 0; q2 < 2; ++q2) {
        const int rowg = sup * 64 + qg * 32 + q2 * 16 + lr;
        unsigned short* np_ = ns0 + ((size_t)((b << 12) + rowg)) * 256 + h * 64;
        #pragma unroll
        for (int m2 = 0; m2 < 4; ++m2) {
          uint2 pk2; pk2.x = cvtpk(cacc[q2][m2][0], cacc[q2][m2][1]);
          pk2.y = cvtpk(cacc[q2][m2][2], cacc[q2][m2][3]);
          *(uint2*)&np_[m2 * 16 + grp * 4] = pk2;
        }
        if (grp == 0) lb0[(bh << 12) + rowg] = lacc[q2][0] + lred[qg][q2][lr];
      }
    } else {
      #pragma unroll
      for (int q2 = 0; q2 < 2; ++q2) {
        const int rowg = sup * 64 + qg * 32 + q2 * 16 + lr;   // >= 2048
        unsigned short* np_ = ns2 + ((size_t)((b << 11) + (rowg - 2048))) * 256 + h * 64;
        #pragma unroll
        for (int m2 = 0; m2 < 4; ++m2) {
          uint2 pk2; pk2.x = cvtpk(cacc[q2][m2][0], cacc[q2][m2][1]);
          pk2.y = cvtpk(cacc[q2][m2][2], cacc[q2][m2][3]);
          *(uint2*)&np_[m2 * 16 + grp * 4] = pk2;
        }
        if (grp == 0) lb2[(bh << 11) + (rowg - 2048)] = lacc[q2][0] + lred[qg][q2][lr];
      }
    }
  }
}

// ---------------- Kernel 3: output projection + residual + LayerNorm (MFMA) ----------------
__global__ __launch_bounds__(256, 4) void oproj_ln(
    const unsigned short* __restrict__ ns0, const unsigned short* __restrict__ ns2,
    const float* __restrict__ lb0, const float* __restrict__ lb2,
    const unsigned short* __restrict__ Wot,
    const float* __restrict__ bo, const float* __restrict__ query,
    const float* __restrict__ gamma, const float* __restrict__ beta,
    float* __restrict__ out)
{
  __shared__ __align__(16) float redS[32][4];
  __shared__ __align__(16) float redQ[32][4];

  const int t = threadIdx.x;
  const int w = t >> 6, l = t & 63, lr = l & 15, grp = l >> 4;
  const long r0 = (long)blockIdx.x * 32;
  const int n0c = w * 64;
  const int b = (int)(r0 >> 12);
  const bool heavy = ((r0 >> 11) & 1) != 0;

  float invl[2][4];
  #pragma unroll
  for (int mt = 0; mt < 2; ++mt) {
    const int grow = (int)r0 + mt * 16 + lr;
    #pragma unroll
    for (int h = 0; h < 4; ++h) {
      float lv = lb0[((b * 4 + h) << 12) + (grow & 4095)];
      if (heavy) lv += lb2[((b * 4 + h) << 11) + (grow & 2047)];
      invl[mt][h] = 1.0f / lv;
    }
  }

  f32x4 acc[2][4] = {};

  #pragma unroll
  for (int k0 = 0; k0 < 256; k0 += 32) {
    s16x8 bfr[2];
    #pragma unroll
    for (int mt = 0; mt < 2; ++mt) {
      const int grow = (int)r0 + mt * 16 + lr;
      const int c = k0 + grp * 8;
      f32x4 a0 = {0.f, 0.f, 0.f, 0.f}, a1 = {0.f, 0.f, 0.f, 0.f};
      acc8(ns0 + (size_t)grow * 256 + c, a0, a1);
      if (heavy)
        acc8(ns2 + ((size_t)((b << 11) + (grow & 2047))) * 256 + c, a0, a1);
      const float iv = invl[mt][k0 >> 6];
      a0 *= iv; a1 *= iv;
      union { u32 wd[4]; s16x8 v; } bb;
      bb.wd[0] = cvtpk(a0[0], a0[1]);
      bb.wd[1] = cvtpk(a0[2], a0[3]);
      bb.wd[2] = cvtpk(a1[0], a1[1]);
      bb.wd[3] = cvtpk(a1[2], a1[3]);
      bfr[mt] = bb.v;
    }
    #pragma unroll
    for (int nt = 0; nt < 4; ++nt) {
      s16x8 af = *(const s16x8*)(Wot + (size_t)(n0c + nt * 16 + lr) * 256 + k0 + grp * 8);
      acc[0][nt] = __builtin_amdgcn_mfma_f32_16x16x32_bf16(af, bfr[0], acc[0][nt], 0, 0, 0);
      acc[1][nt] = __builtin_amdgcn_mfma_f32_16x16x32_bf16(af, bfr[1], acc[1][nt], 0, 0, 0);
    }
  }

  float sm[2] = {0.f, 0.f}, sq[2] = {0.f, 0.f};
  #pragma unroll
  for (int mt = 0; mt < 2; ++mt) {
    const long s = r0 + mt * 16 + lr;
    #pragma unroll
    for (int nt = 0; nt < 4; ++nt) {
      const int n = n0c + nt * 16 + grp * 4;
      f32x4 v = acc[mt][nt] + *(const f32x4*)&bo[n] + *(const f32x4*)&query[s * 256 + n];
      acc[mt][nt] = v;
      sm[mt] += v[0] + v[1] + v[2] + v[3];
      sq[mt] += v[0]*v[0] + v[1]*v[1] + v[2]*v[2] + v[3]*v[3];
    }
    sm[mt] += __shfl_xor(sm[mt], 16); sm[mt] += __shfl_xor(sm[mt], 32);
    sq[mt] += __shfl_xor(sq[mt], 16); sq[mt] += __shfl_xor(sq[mt], 32);
  }
  if (grp == 0) {
    redS[0 * 16 + lr][w] = sm[0]; redQ[0 * 16 + lr][w] = sq[0];
    redS[1 * 16 + lr][w] = sm[1]; redQ[1 * 16 + lr][w] = sq[1];
  }
  __syncthreads();

  #pragma unroll
  for (int mt = 0; mt < 2; ++mt) {
    f32x4 s4 = *(const f32x4*)&redS[mt * 16 + lr][0];
    f32x4 q4 = *(const f32x4*)&redQ[mt * 16 + lr][0];
    const float tot = s4[0] + s4[1] + s4[2] + s4[3];
    const float tq  = q4[0] + q4[1] + q4[2] + q4[3];
    const float mu  = tot * 0.00390625f;
    const float var = tq * 0.00390625f - mu * mu;
    const float rs  = rsqrtf(var + 1.0e-3f);
    const long s = r0 + mt * 16 + lr;
    #pragma unroll
    for (int nt = 0; nt < 4; ++nt) {
      const int n = n0c + nt * 16 + grp * 4;
      f32x4 g = *(const f32x4*)&gamma[n];
      f32x4 bt = *(const f32x4*)&beta[n];
      f32x4 o = (acc[mt][nt] - mu) * rs * g + bt;
      *(f32x4*)&out[s * 256 + n] = o;
    }
  }
}

extern "C" void kernel_launch(void* const* d_in, const int* in_sizes, int n_in,
                              void* d_out, int out_size, void* d_ws, size_t ws_size,
                              hipStream_t stream) {
  const float* query = (const float*)d_in[0];
  const float* value = (const float*)d_in[1];
  const float* Wq    = (const float*)d_in[2];
  const float* bq    = (const float*)d_in[3];
  const float* Wk    = (const float*)d_in[4];
  const float* bk    = (const float*)d_in[5];
  const float* Wv    = (const float*)d_in[6];
  const float* bv    = (const float*)d_in[7];
  const float* Wo    = (const float*)d_in[8];
  const float* bo    = (const float*)d_in[9];
  const float* gamma = (const float*)d_in[10];
  const float* beta  = (const float*)d_in[11];
  float* out = (float*)d_out;

  char* ws = (char*)d_ws;
  unsigned short* qb  = (unsigned short*)ws;                          //  8 MiB bf16 [bh][s][dk]
  unsigned short* kbs = (unsigned short*)(ws + ((size_t)8  << 20));   //  8 MiB bf16 chunked K
  unsigned short* vts = (unsigned short*)(ws + ((size_t)16 << 20));   //  8 MiB bf16 chunked V^T
  unsigned short* ns0 = (unsigned short*)(ws + ((size_t)24 << 20));   //  8 MiB bf16 [b*4096][256]
  unsigned short* ns2 = (unsigned short*)(ws + ((size_t)32 << 20));   //  4 MiB bf16 [b*2048][256]
  float* lb0 = (float*)(ws + ((size_t)36 << 20));                     // 256 KiB f32 [16][4096]
  float* lb2 = (float*)(ws + ((size_t)36 << 20) + ((size_t)256 << 10)); // 128 KiB f32 [16][2048]
  unsigned short* Wt  = (unsigned short*)(ws + ((size_t)36 << 20) + ((size_t)512 << 10)); // 384 KiB
  unsigned short* Wot = Wt + (size_t)768 * 256;                       // 128 KiB

  wprep<<<64, 256, 0, stream>>>(Wq, Wk, Wv, Wo, Wt, Wot);
  qkv_mfma<<<768, 256, 0, stream>>>(query, value, Wt, bq, bk, bv, qb, kbs, vts);
  attn<<<1024, 256, 0, stream>>>(qb, kbs, vts, ns0, ns2, lb0, lb2);
  oproj_ln<<<512, 256, 0, stream>>>(ns0, ns2, lb0, lb2, Wot, bo, query, gamma, beta, out);
}